// Round 11
// baseline (444.606 us; speedup 1.0000x reference)
//
#include <hip/hip_runtime.h>
#include <math.h>

#define NH   16
#define SQL  4096
#define SKL  4096
#define DK   64
#define QB   128
#define KB   64
#define KSPLIT 4
#define KQ    (SKL / KSPLIT)      // 1024 cols per quarter
#define NKT   (KQ / KB)           // 16 K-tiles per quarter

// Q pre-scale: MFMA then yields dot' = s * 0.5*log2(e), so exp2(dot') = exp(s/2)
#define QSCALE  0.090168440f      // 0.125 * 0.5 * log2(e)
#define UNSCALE 1.3862943611f     // 2*ln2 : dot' -> s

#define RSUMN    (NH * 32 * KSPLIT)       // 2048 block partial sums
#define ROWFLOAT (NH * KSPLIT * SQL)      // 262144 floats per row-stat array
#define STATS_BYTES ((size_t)(RSUMN + 3 * ROWFLOAT) * 4)   // 3,153,920 B

#define KIMG 8192                          // K tile image: 64 rows x 128 B (swizzled)
#define KPRE_BYTES ((size_t)NH * (SKL / KB) * KIMG)   // 8.39 MB

typedef __bf16 bf16x8 __attribute__((ext_vector_type(8)));
typedef __bf16 bf16x4 __attribute__((ext_vector_type(4)));
typedef float  f32x4  __attribute__((ext_vector_type(4)));
typedef float  f32x2  __attribute__((ext_vector_type(2)));

#if __has_builtin(__builtin_amdgcn_exp2f)
#define EXP2(x) __builtin_amdgcn_exp2f(x)
#else
#define EXP2(x) exp2f(x)
#endif

static __device__ __forceinline__ f32x2 pk_fma(f32x2 a, f32x2 b, f32x2 c) {
#if __has_builtin(__builtin_elementwise_fma)
    return __builtin_elementwise_fma(a, b, c);
#else
    f32x2 r; r[0] = fmaf(a[0], b[0], c[0]); r[1] = fmaf(a[1], b[1], c[1]); return r;
#endif
}
static __device__ __forceinline__ f32x2 pk_max(f32x2 a, f32x2 b) {
#if __has_builtin(__builtin_elementwise_max)
    return __builtin_elementwise_max(a, b);
#else
    f32x2 r; r[0] = fmaxf(a[0], b[0]); r[1] = fmaxf(a[1], b[1]); return r;
#endif
}

// XOR-swizzled byte address into a [rows][64] bf16 tile (row stride 128 B).
__device__ __forceinline__ int swz(int row, int col_bytes) {
    return ((row << 7) + col_bytes) ^ ((row & 7) << 4);
}

// async 16B global -> LDS (direct DMA). LDS linear; swizzle baked into SOURCE.
static __device__ __forceinline__ void gld16(void* l, const void* g) {
#if __has_builtin(__builtin_amdgcn_global_load_lds)
    __builtin_amdgcn_global_load_lds(
        (const __attribute__((address_space(1))) unsigned int*)g,
        (__attribute__((address_space(3))) unsigned int*)l,
        16, 0, 0);
#else
    *reinterpret_cast<float4*>(l) = *reinterpret_cast<const float4*>(g);
#endif
}

// Load one A-fragment (8 dims) straight from raw fp32 Q, scaled to bf16.
static __device__ __forceinline__ bf16x8 loadA(const float* __restrict__ Q,
                                               int grow, int d0) {
    const float* p = Q + (size_t)grow * DK + d0;
    float4 a = *reinterpret_cast<const float4*>(p);
    float4 b = *reinterpret_cast<const float4*>(p + 4);
    bf16x8 v;
    v[0]=(__bf16)(a.x*QSCALE); v[1]=(__bf16)(a.y*QSCALE);
    v[2]=(__bf16)(a.z*QSCALE); v[3]=(__bf16)(a.w*QSCALE);
    v[4]=(__bf16)(b.x*QSCALE); v[5]=(__bf16)(b.y*QSCALE);
    v[6]=(__bf16)(b.z*QSCALE); v[7]=(__bf16)(b.w*QSCALE);
    return v;
}

// Kernel 0: pre-pack K into bf16 swizzled tile images (K only; Q goes direct).
__global__ __launch_bounds__(512) void dtp_prepack_k(const float* __restrict__ K,
                                                     unsigned char* __restrict__ Kpre) {
    const int i   = blockIdx.x * 512 + threadIdx.x;   // 0..524287
    const int c16 = i & 7;            // 16B chunk within row (8 dims)
    const int rg  = i >> 3;           // h*4096 + row
    const int h   = rg >> 12;
    const int row = rg & 4095;

    const float* ks = K + (size_t)rg * DK + c16 * 8;
    float4 a = *reinterpret_cast<const float4*>(ks);
    float4 b = *reinterpret_cast<const float4*>(ks + 4);
    bf16x8 kv;
    kv[0]=(__bf16)a.x; kv[1]=(__bf16)a.y; kv[2]=(__bf16)a.z; kv[3]=(__bf16)a.w;
    kv[4]=(__bf16)b.x; kv[5]=(__bf16)b.y; kv[6]=(__bf16)b.z; kv[7]=(__bf16)b.w;
    *reinterpret_cast<bf16x8*>(
        &Kpre[(size_t)h * 64 * KIMG + (size_t)(row >> 6) * KIMG + swz(row & 63, c16 * 16)]) = kv;
}

// Kernel 1: per-(head, q-block, k-quarter) streaming score statistics.
// 4 waves x 32 q-rows (R7-verified hot loop). Q direct-to-register.
// LDS = K double-buffer only (16.5 KB) -> 8 blocks/CU, 32 waves/CU.
__global__ __launch_bounds__(256, 8) void dtp_stats_glds(const float* __restrict__ Q,
                                                         const unsigned char* __restrict__ Kpre,
                                                         float* __restrict__ RSUM,
                                                         float* __restrict__ RMX,
                                                         float* __restrict__ RS1,
                                                         float* __restrict__ RS2) {
    __shared__ __align__(16) unsigned char Ks[2][KIMG];     // 2 x 8 KB
    __shared__ float red[16];

    const int qb   = blockIdx.x;   // 0..31
    const int h    = blockIdx.y;   // 0..15
    const int qt   = blockIdx.z;   // 0..3 (K quarter)
    const int tid  = threadIdx.x;
    const int lane = tid & 63;
    const int w    = tid >> 6;     // wave 0..3 -> q-rows w*32..w*32+31
    const int l15  = lane & 15;
    const int lg   = lane >> 4;    // 0..3

    const unsigned char* Kg = Kpre + (size_t)h * 64 * KIMG + (size_t)qt * NKT * KIMG;
    const int off = tid * 16;

    // ---- issue K tile 0 DMA ----
    gld16(&Ks[0][off],        Kg + off);
    gld16(&Ks[0][off + 4096], Kg + off + 4096);

    // ---- A fragments straight from raw Q (prologue only) ----
    bf16x8 aF[2][2];
    #pragma unroll
    for (int rt = 0; rt < 2; ++rt) {
        int grow = h * SQL + qb * QB + w * 32 + rt * 16 + l15;
        aF[rt][0] = loadA(Q, grow, 0 * 32 + lg * 8);
        aF[rt][1] = loadA(Q, grow, 1 * 32 + lg * 8);
    }
    __syncthreads();   // drains vmcnt -> Ks[0] valid (Q loads also done)

    // packed per-lane stats [rt][pair]: pair0 = acc regs (0,1), pair1 = (2,3)
    f32x2 rsum[2][2], rmx[2][2], rs1[2][2], rs2[2][2];
    #pragma unroll
    for (int rt = 0; rt < 2; ++rt)
        #pragma unroll
        for (int p = 0; p < 2; ++p) {
            rsum[rt][p] = (f32x2){0.f, 0.f};
            rmx[rt][p]  = (f32x2){-3.0e38f, -3.0e38f};
            rs1[rt][p]  = (f32x2){0.f, 0.f};
            rs2[rt][p]  = (f32x2){0.f, 0.f};
        }

    for (int t = 0; t < NKT; ++t) {
        const int b = t & 1;

        // ---- issue DMA for tile t+1 into inactive buffer ----
        if (t + 1 < NKT) {
            const unsigned char* Kt = Kg + (size_t)(t + 1) * KIMG;
            gld16(&Ks[b ^ 1][off],        Kt + off);
            gld16(&Ks[b ^ 1][off + 4096], Kt + off + 4096);
        }

        // ---- 32x64 score tile: 16 mfma, fold immediately (R7 verified) ----
        #pragma unroll
        for (int ct = 0; ct < 4; ++ct) {
            int rr = ct * 16 + l15;
            bf16x8 b0 = *reinterpret_cast<const bf16x8*>(&Ks[b][swz(rr, 0 * 64 + lg * 16)]);
            bf16x8 b1 = *reinterpret_cast<const bf16x8*>(&Ks[b][swz(rr, 1 * 64 + lg * 16)]);
            #pragma unroll
            for (int rt = 0; rt < 2; ++rt) {
                f32x4 a = {0.f, 0.f, 0.f, 0.f};
                a = __builtin_amdgcn_mfma_f32_16x16x32_bf16(aF[rt][0], b0, a, 0, 0, 0);
                a = __builtin_amdgcn_mfma_f32_16x16x32_bf16(aF[rt][1], b1, a, 0, 0, 0);
                f32x2 v01 = __builtin_shufflevector(a, a, 0, 1);
                f32x2 v23 = __builtin_shufflevector(a, a, 2, 3);
                rsum[rt][0] += v01; rsum[rt][1] += v23;
                rmx[rt][0] = pk_max(rmx[rt][0], v01);
                rmx[rt][1] = pk_max(rmx[rt][1], v23);
                f32x2 e01, e23;
                e01[0] = EXP2(v01[0]); e01[1] = EXP2(v01[1]);
                e23[0] = EXP2(v23[0]); e23[1] = EXP2(v23[1]);
                rs1[rt][0] += e01; rs1[rt][1] += e23;
                rs2[rt][0] = pk_fma(e01, e01, rs2[rt][0]);
                rs2[rt][1] = pk_fma(e23, e23, rs2[rt][1]);
            }
        }

        __syncthreads();   // reads of Ks[b] done; DMA into Ks[b^1] drained
    }

    // ---- reduce across the 16 column-lanes (bits 0..3 of lane id) ----
    #pragma unroll
    for (int m = 1; m < 16; m <<= 1) {
        #pragma unroll
        for (int rt = 0; rt < 2; ++rt)
            #pragma unroll
            for (int c = 0; c < 2; ++c) {
                rsum[rt][c][0] += __shfl_xor(rsum[rt][c][0], m, 64);
                rsum[rt][c][1] += __shfl_xor(rsum[rt][c][1], m, 64);
                rmx[rt][c][0]   = fmaxf(rmx[rt][c][0], __shfl_xor(rmx[rt][c][0], m, 64));
                rmx[rt][c][1]   = fmaxf(rmx[rt][c][1], __shfl_xor(rmx[rt][c][1], m, 64));
                rs1[rt][c][0]  += __shfl_xor(rs1[rt][c][0], m, 64);
                rs1[rt][c][1]  += __shfl_xor(rs1[rt][c][1], m, 64);
                rs2[rt][c][0]  += __shfl_xor(rs2[rt][c][0], m, 64);
                rs2[rt][c][1]  += __shfl_xor(rs2[rt][c][1], m, 64);
            }
    }

    // row-stat layout: rb = (h*KSPLIT + qt)*SQL + global_row_in_head
    const size_t rowbase = ((size_t)(h * KSPLIT + qt)) * SQL + (size_t)qb * QB;
    if (l15 == 0) {
        float bs = 0.f;
        #pragma unroll
        for (int rt = 0; rt < 2; ++rt) {
            const size_t rb = rowbase + (w * 32 + rt * 16 + lg * 4);
            float4 mx = {rmx[rt][0][0] * UNSCALE, rmx[rt][0][1] * UNSCALE,
                         rmx[rt][1][0] * UNSCALE, rmx[rt][1][1] * UNSCALE};
            float4 s1 = {rs1[rt][0][0], rs1[rt][0][1], rs1[rt][1][0], rs1[rt][1][1]};
            float4 s2 = {rs2[rt][0][0], rs2[rt][0][1], rs2[rt][1][0], rs2[rt][1][1]};
            *reinterpret_cast<float4*>(&RMX[rb]) = mx;
            *reinterpret_cast<float4*>(&RS1[rb]) = s1;
            *reinterpret_cast<float4*>(&RS2[rb]) = s2;
            bs += (rsum[rt][0][0] + rsum[rt][0][1]) + (rsum[rt][1][0] + rsum[rt][1][1]);
        }
        red[w * 4 + lg] = bs;
    }
    __syncthreads();
    if (tid == 0) {
        float bs = 0.f;
        #pragma unroll
        for (int i = 0; i < 16; ++i) bs += red[i];
        RSUM[(h * 32 + qb) * KSPLIT + qt] = bs * UNSCALE;
    }
}

// Fallback (ws too small): same geometry, K reg-staged + converted in-loop.
__global__ __launch_bounds__(256, 4) void dtp_stats_reg(const float* __restrict__ Q,
                                                        const float* __restrict__ K,
                                                        float* __restrict__ RSUM,
                                                        float* __restrict__ RMX,
                                                        float* __restrict__ RS1,
                                                        float* __restrict__ RS2) {
    __shared__ __align__(16) unsigned char Ks[2][KIMG];
    __shared__ float red[16];

    const int qb = blockIdx.x, h = blockIdx.y, qt = blockIdx.z;
    const int tid = threadIdx.x, lane = tid & 63, w = tid >> 6;
    const int l15 = lane & 15, lg = lane >> 4;
    const int sc4 = tid & 15, sr = tid >> 4;   // 16 chunks x 16 row-groups

    const float* Kq = K + ((size_t)h * SKL + (size_t)qt * KQ) * DK;

    // prologue: tile0 -> regs -> Ks[0]; prefetch tile1 -> regs
    float4 kreg[4];
    #pragma unroll
    for (int j = 0; j < 4; ++j)
        kreg[j] = *reinterpret_cast<const float4*>(Kq + (size_t)(sr + 16 * j) * DK + sc4 * 4);
    #pragma unroll
    for (int j = 0; j < 4; ++j) {
        int r = sr + 16 * j;
        bf16x4 hv;
        hv[0] = (__bf16)kreg[j].x; hv[1] = (__bf16)kreg[j].y;
        hv[2] = (__bf16)kreg[j].z; hv[3] = (__bf16)kreg[j].w;
        *reinterpret_cast<bf16x4*>(&Ks[0][swz(r, sc4 * 8)]) = hv;
    }
    #pragma unroll
    for (int j = 0; j < 4; ++j)
        kreg[j] = *reinterpret_cast<const float4*>(Kq + (size_t)(KB + sr + 16 * j) * DK + sc4 * 4);

    bf16x8 aF[2][2];
    #pragma unroll
    for (int rt = 0; rt < 2; ++rt) {
        int grow = h * SQL + qb * QB + w * 32 + rt * 16 + l15;
        aF[rt][0] = loadA(Q, grow, 0 * 32 + lg * 8);
        aF[rt][1] = loadA(Q, grow, 1 * 32 + lg * 8);
    }
    __syncthreads();

    f32x2 rsum[2][2], rmx[2][2], rs1[2][2], rs2[2][2];
    #pragma unroll
    for (int rt = 0; rt < 2; ++rt)
        #pragma unroll
        for (int p = 0; p < 2; ++p) {
            rsum[rt][p] = (f32x2){0.f, 0.f};
            rmx[rt][p]  = (f32x2){-3.0e38f, -3.0e38f};
            rs1[rt][p]  = (f32x2){0.f, 0.f};
            rs2[rt][p]  = (f32x2){0.f, 0.f};
        }

    for (int t = 0; t < NKT; ++t) {
        const int b = t & 1;
        if (t + 1 < NKT) {
            #pragma unroll
            for (int j = 0; j < 4; ++j) {
                int r = sr + 16 * j;
                bf16x4 hv;
                hv[0] = (__bf16)kreg[j].x; hv[1] = (__bf16)kreg[j].y;
                hv[2] = (__bf16)kreg[j].z; hv[3] = (__bf16)kreg[j].w;
                *reinterpret_cast<bf16x4*>(&Ks[b ^ 1][swz(r, sc4 * 8)]) = hv;
            }
            if (t + 2 < NKT) {
                const float* Kt = Kq + (size_t)(t + 2) * KB * DK;
                #pragma unroll
                for (int j = 0; j < 4; ++j)
                    kreg[j] = *reinterpret_cast<const float4*>(Kt + (size_t)(sr + 16 * j) * DK + sc4 * 4);
            }
        }
        #pragma unroll
        for (int ct = 0; ct < 4; ++ct) {
            int rr = ct * 16 + l15;
            bf16x8 b0 = *reinterpret_cast<const bf16x8*>(&Ks[b][swz(rr, 0 * 64 + lg * 16)]);
            bf16x8 b1 = *reinterpret_cast<const bf16x8*>(&Ks[b][swz(rr, 1 * 64 + lg * 16)]);
            #pragma unroll
            for (int rt = 0; rt < 2; ++rt) {
                f32x4 a = {0.f, 0.f, 0.f, 0.f};
                a = __builtin_amdgcn_mfma_f32_16x16x32_bf16(aF[rt][0], b0, a, 0, 0, 0);
                a = __builtin_amdgcn_mfma_f32_16x16x32_bf16(aF[rt][1], b1, a, 0, 0, 0);
                f32x2 v01 = __builtin_shufflevector(a, a, 0, 1);
                f32x2 v23 = __builtin_shufflevector(a, a, 2, 3);
                rsum[rt][0] += v01; rsum[rt][1] += v23;
                rmx[rt][0] = pk_max(rmx[rt][0], v01);
                rmx[rt][1] = pk_max(rmx[rt][1], v23);
                f32x2 e01, e23;
                e01[0] = EXP2(v01[0]); e01[1] = EXP2(v01[1]);
                e23[0] = EXP2(v23[0]); e23[1] = EXP2(v23[1]);
                rs1[rt][0] += e01; rs1[rt][1] += e23;
                rs2[rt][0] = pk_fma(e01, e01, rs2[rt][0]);
                rs2[rt][1] = pk_fma(e23, e23, rs2[rt][1]);
            }
        }
        __syncthreads();
    }

    #pragma unroll
    for (int m = 1; m < 16; m <<= 1) {
        #pragma unroll
        for (int rt = 0; rt < 2; ++rt)
            #pragma unroll
            for (int c = 0; c < 2; ++c) {
                rsum[rt][c][0] += __shfl_xor(rsum[rt][c][0], m, 64);
                rsum[rt][c][1] += __shfl_xor(rsum[rt][c][1], m, 64);
                rmx[rt][c][0]   = fmaxf(rmx[rt][c][0], __shfl_xor(rmx[rt][c][0], m, 64));
                rmx[rt][c][1]   = fmaxf(rmx[rt][c][1], __shfl_xor(rmx[rt][c][1], m, 64));
                rs1[rt][c][0]  += __shfl_xor(rs1[rt][c][0], m, 64);
                rs1[rt][c][1]  += __shfl_xor(rs1[rt][c][1], m, 64);
                rs2[rt][c][0]  += __shfl_xor(rs2[rt][c][0], m, 64);
                rs2[rt][c][1]  += __shfl_xor(rs2[rt][c][1], m, 64);
            }
    }

    const size_t rowbase = ((size_t)(h * KSPLIT + qt)) * SQL + (size_t)qb * QB;
    if (l15 == 0) {
        float bs = 0.f;
        #pragma unroll
        for (int rt = 0; rt < 2; ++rt) {
            const size_t rb = rowbase + (w * 32 + rt * 16 + lg * 4);
            float4 mx = {rmx[rt][0][0] * UNSCALE, rmx[rt][0][1] * UNSCALE,
                         rmx[rt][1][0] * UNSCALE, rmx[rt][1][1] * UNSCALE};
            float4 s1 = {rs1[rt][0][0], rs1[rt][0][1], rs1[rt][1][0], rs1[rt][1][1]};
            float4 s2 = {rs2[rt][0][0], rs2[rt][0][1], rs2[rt][1][0], rs2[rt][1][1]};
            *reinterpret_cast<float4*>(&RMX[rb]) = mx;
            *reinterpret_cast<float4*>(&RS1[rb]) = s1;
            *reinterpret_cast<float4*>(&RS2[rb]) = s2;
            bs += (rsum[rt][0][0] + rsum[rt][0][1]) + (rsum[rt][1][0] + rsum[rt][1][1]);
        }
        red[w * 4 + lg] = bs;
    }
    __syncthreads();
    if (tid == 0) {
        float bs = 0.f;
        #pragma unroll
        for (int i = 0; i < 16; ++i) bs += red[i];
        RSUM[(h * 32 + qb) * KSPLIT + qt] = bs * UNSCALE;
    }
}

// Kernel 2: per-head, combine 4 K-quarter partials per row, reduce, MLP.
__global__ __launch_bounds__(256) void dtp_finalize(const float* __restrict__ RSUM,
                                                    const float* __restrict__ RMX,
                                                    const float* __restrict__ RS1,
                                                    const float* __restrict__ RS2,
                                                    const float* __restrict__ W1,
                                                    const float* __restrict__ b1,
                                                    const float* __restrict__ W2,
                                                    const float* __restrict__ b2,
                                                    float* __restrict__ out) {
    const int h   = blockIdx.x;
    const int tid = threadIdx.x;
    const float invSK  = 1.0f / (float)SKL;
    const float invSK1 = 1.0f / (float)(SKL - 1);

    float sm = 0.f, sv = 0.f;
    #pragma unroll
    for (int j = 0; j < 16; ++j) {
        int r = tid + 256 * j;   // 0..4095
        size_t i0 = ((size_t)h * KSPLIT + 0) * SQL + r;
        size_t i1 = i0 + SQL;
        size_t i2 = i0 + 2 * SQL;
        size_t i3 = i0 + 3 * SQL;
        float mx = fmaxf(fmaxf(RMX[i0], RMX[i1]), fmaxf(RMX[i2], RMX[i3]));
        float s1 = (RS1[i0] + RS1[i1]) + (RS1[i2] + RS1[i3]);
        float s2 = (RS2[i0] + RS2[i1]) + (RS2[i2] + RS2[i3]);
        sm += mx;
        sv += (s2 / (s1 * s1) - invSK) * invSK1;
    }
    // 128 block-sums per head (32 qb x 4 quarters)
    float ss = (tid < 128) ? RSUM[h * 128 + tid] : 0.f;

    #pragma unroll
    for (int m = 1; m < 64; m <<= 1) {
        sm += __shfl_xor(sm, m, 64);
        sv += __shfl_xor(sv, m, 64);
        ss += __shfl_xor(ss, m, 64);
    }
    __shared__ float redm[4], redv[4], reds[4];
    const int wv = tid >> 6;
    if ((tid & 63) == 0) { redm[wv] = sm; redv[wv] = sv; reds[wv] = ss; }
    __syncthreads();
    if (tid == 0) {
        float tsm = redm[0] + redm[1] + redm[2] + redm[3];
        float tsv = redv[0] + redv[1] + redv[2] + redv[3];
        float tss = reds[0] + reds[1];   // waves 0,1 loaded RSUM (tid<128)
        float mean_sim = tss / ((float)SQL * (float)SKL);
        float max_sim  = tsm / (float)SQL;
        float entropy  = tsv / (float)SQL;
        mean_sim = fminf(fmaxf(mean_sim, -10.f), 10.f);
        max_sim  = fminf(fmaxf(max_sim,  -10.f), 10.f);
        entropy  = fminf(fmaxf(entropy,    0.f), 1.f);
        float raw = b2[0];
        #pragma unroll
        for (int i = 0; i < 16; ++i) {
            float a = b1[i] + W1[i*3+0] * mean_sim + W1[i*3+1] * max_sim + W1[i*3+2] * entropy;
            raw += W2[i] * tanhf(a);
        }
        float t = 0.1f + 0.9f / (1.0f + __expf(-raw));
        t = fminf(fmaxf(t, 0.1f), 1.0f);
        out[h] = t;
    }
}

extern "C" void kernel_launch(void* const* d_in, const int* in_sizes, int n_in,
                              void* d_out, int out_size, void* d_ws, size_t ws_size,
                              hipStream_t stream) {
    const float* Q  = (const float*)d_in[0];
    const float* K  = (const float*)d_in[1];
    const float* W1 = (const float*)d_in[2];
    const float* b1 = (const float*)d_in[3];
    const float* W2 = (const float*)d_in[4];
    const float* b2 = (const float*)d_in[5];
    float* out      = (float*)d_out;

    float* RSUM = (float*)d_ws;                 // 2048 floats
    float* RMX  = RSUM + RSUMN;                 // 262144
    float* RS1  = RMX + ROWFLOAT;               // 262144
    float* RS2  = RS1 + ROWFLOAT;               // 262144

    const size_t need = STATS_BYTES + KPRE_BYTES;   // ~11.5 MB
    dim3 grid(SQL / QB, NH, KSPLIT);  // (32, 16, 4) = 2048 blocks

    if (ws_size >= need) {
        unsigned char* Kpre = (unsigned char*)d_ws + STATS_BYTES;
        dtp_prepack_k<<<1024, 512, 0, stream>>>(K, Kpre);
        dtp_stats_glds<<<grid, 256, 0, stream>>>(Q, Kpre, RSUM, RMX, RS1, RS2);
    } else {
        dtp_stats_reg<<<grid, 256, 0, stream>>>(Q, K, RSUM, RMX, RS1, RS2);
    }
    dtp_finalize<<<NH, 256, 0, stream>>>(RSUM, RMX, RS1, RS2, W1, b1, W2, b2, out);
}

// Round 12
// 78.773 us; speedup vs baseline: 5.6441x; 5.6441x over previous
//
#include <hip/hip_runtime.h>
#include <math.h>

#define NH   16
#define SQL  4096
#define SKL  4096
#define DK   64
#define QB   128
#define KB   64
#define KSPLIT 4
#define KQ    (SKL / KSPLIT)      // 1024 cols per quarter
#define NKT   (KQ / KB)           // 16 K-tiles per quarter

// Q pre-scale: MFMA then yields dot' = s * 0.5*log2(e), so exp2(dot') = exp(s/2)
#define QSCALE  0.090168440f      // 0.125 * 0.5 * log2(e)
#define UNSCALE 1.3862943611f     // 2*ln2 : dot' -> s

#define RSUMN    (NH * 32 * KSPLIT)       // 2048 block partial sums
#define ROWFLOAT (NH * KSPLIT * SQL)      // 262144 floats per row-stat array
#define STATS_BYTES ((size_t)(RSUMN + 3 * ROWFLOAT) * 4)   // 3,153,920 B

#define KIMG 8192                          // K tile image: 64 rows x 128 B (swizzled)
#define KPRE_BYTES ((size_t)NH * (SKL / KB) * KIMG)   // 8.39 MB

typedef __bf16 bf16x8 __attribute__((ext_vector_type(8)));
typedef __bf16 bf16x4 __attribute__((ext_vector_type(4)));
typedef float  f32x4  __attribute__((ext_vector_type(4)));
typedef float  f32x2  __attribute__((ext_vector_type(2)));

#if __has_builtin(__builtin_amdgcn_exp2f)
#define EXP2(x) __builtin_amdgcn_exp2f(x)
#else
#define EXP2(x) exp2f(x)
#endif

static __device__ __forceinline__ f32x2 pk_fma(f32x2 a, f32x2 b, f32x2 c) {
#if __has_builtin(__builtin_elementwise_fma)
    return __builtin_elementwise_fma(a, b, c);
#else
    f32x2 r; r[0] = fmaf(a[0], b[0], c[0]); r[1] = fmaf(a[1], b[1], c[1]); return r;
#endif
}
static __device__ __forceinline__ f32x2 pk_max(f32x2 a, f32x2 b) {
#if __has_builtin(__builtin_elementwise_max)
    return __builtin_elementwise_max(a, b);
#else
    f32x2 r; r[0] = fmaxf(a[0], b[0]); r[1] = fmaxf(a[1], b[1]); return r;
#endif
}

// XOR-swizzled byte address into a [rows][64] bf16 tile (row stride 128 B).
__device__ __forceinline__ int swz(int row, int col_bytes) {
    return ((row << 7) + col_bytes) ^ ((row & 7) << 4);
}

// async 16B global -> LDS (direct DMA). LDS linear; swizzle baked into SOURCE.
static __device__ __forceinline__ void gld16(void* l, const void* g) {
#if __has_builtin(__builtin_amdgcn_global_load_lds)
    __builtin_amdgcn_global_load_lds(
        (const __attribute__((address_space(1))) unsigned int*)g,
        (__attribute__((address_space(3))) unsigned int*)l,
        16, 0, 0);
#else
    *reinterpret_cast<float4*>(l) = *reinterpret_cast<const float4*>(g);
#endif
}

// Load one A-fragment (8 dims) straight from raw fp32 Q, scaled to bf16.
static __device__ __forceinline__ bf16x8 loadA(const float* __restrict__ Q,
                                               int grow, int d0) {
    const float* p = Q + (size_t)grow * DK + d0;
    float4 a = *reinterpret_cast<const float4*>(p);
    float4 b = *reinterpret_cast<const float4*>(p + 4);
    bf16x8 v;
    v[0]=(__bf16)(a.x*QSCALE); v[1]=(__bf16)(a.y*QSCALE);
    v[2]=(__bf16)(a.z*QSCALE); v[3]=(__bf16)(a.w*QSCALE);
    v[4]=(__bf16)(b.x*QSCALE); v[5]=(__bf16)(b.y*QSCALE);
    v[6]=(__bf16)(b.z*QSCALE); v[7]=(__bf16)(b.w*QSCALE);
    return v;
}

// Kernel 0: pre-pack K into bf16 swizzled tile images (K only; Q goes direct).
__global__ __launch_bounds__(512) void dtp_prepack_k(const float* __restrict__ K,
                                                     unsigned char* __restrict__ Kpre) {
    const int i   = blockIdx.x * 512 + threadIdx.x;   // 0..524287
    const int c16 = i & 7;            // 16B chunk within row (8 dims)
    const int rg  = i >> 3;           // h*4096 + row
    const int h   = rg >> 12;
    const int row = rg & 4095;

    const float* ks = K + (size_t)rg * DK + c16 * 8;
    float4 a = *reinterpret_cast<const float4*>(ks);
    float4 b = *reinterpret_cast<const float4*>(ks + 4);
    bf16x8 kv;
    kv[0]=(__bf16)a.x; kv[1]=(__bf16)a.y; kv[2]=(__bf16)a.z; kv[3]=(__bf16)a.w;
    kv[4]=(__bf16)b.x; kv[5]=(__bf16)b.y; kv[6]=(__bf16)b.z; kv[7]=(__bf16)b.w;
    *reinterpret_cast<bf16x8*>(
        &Kpre[(size_t)h * 64 * KIMG + (size_t)(row >> 6) * KIMG + swz(row & 63, c16 * 16)]) = kv;
}

// Kernel 1: per-(head, q-block, k-quarter) streaming score statistics.
// 4 waves x 32 q-rows (R7-verified hot loop). Q direct-to-register.
// LDS = K double-buffer only (16.9 KB); launch_bounds (256,4) -> compiler
// allocates ~64 VGPR (R7 codegen), HW can then co-schedule 8 blocks/CU.
__global__ __launch_bounds__(256, 4) void dtp_stats_glds(const float* __restrict__ Q,
                                                         const unsigned char* __restrict__ Kpre,
                                                         float* __restrict__ RSUM,
                                                         float* __restrict__ RMX,
                                                         float* __restrict__ RS1,
                                                         float* __restrict__ RS2) {
    __shared__ __align__(16) unsigned char Ks[2][KIMG];     // 2 x 8 KB
    __shared__ float red[16];

    const int qb   = blockIdx.x;   // 0..31
    const int h    = blockIdx.y;   // 0..15
    const int qt   = blockIdx.z;   // 0..3 (K quarter)
    const int tid  = threadIdx.x;
    const int lane = tid & 63;
    const int w    = tid >> 6;     // wave 0..3 -> q-rows w*32..w*32+31
    const int l15  = lane & 15;
    const int lg   = lane >> 4;    // 0..3

    const unsigned char* Kg = Kpre + (size_t)h * 64 * KIMG + (size_t)qt * NKT * KIMG;
    const int off = tid * 16;

    // ---- issue K tile 0 DMA ----
    gld16(&Ks[0][off],        Kg + off);
    gld16(&Ks[0][off + 4096], Kg + off + 4096);

    // ---- A fragments straight from raw Q (prologue only) ----
    bf16x8 aF[2][2];
    #pragma unroll
    for (int rt = 0; rt < 2; ++rt) {
        int grow = h * SQL + qb * QB + w * 32 + rt * 16 + l15;
        aF[rt][0] = loadA(Q, grow, 0 * 32 + lg * 8);
        aF[rt][1] = loadA(Q, grow, 1 * 32 + lg * 8);
    }
    __syncthreads();   // drains vmcnt -> Ks[0] valid (Q loads also done)

    // packed per-lane stats [rt][pair]: pair0 = acc regs (0,1), pair1 = (2,3)
    f32x2 rsum[2][2], rmx[2][2], rs1[2][2], rs2[2][2];
    #pragma unroll
    for (int rt = 0; rt < 2; ++rt)
        #pragma unroll
        for (int p = 0; p < 2; ++p) {
            rsum[rt][p] = (f32x2){0.f, 0.f};
            rmx[rt][p]  = (f32x2){-3.0e38f, -3.0e38f};
            rs1[rt][p]  = (f32x2){0.f, 0.f};
            rs2[rt][p]  = (f32x2){0.f, 0.f};
        }

    for (int t = 0; t < NKT; ++t) {
        const int b = t & 1;

        // ---- issue DMA for tile t+1 into inactive buffer ----
        if (t + 1 < NKT) {
            const unsigned char* Kt = Kg + (size_t)(t + 1) * KIMG;
            gld16(&Ks[b ^ 1][off],        Kt + off);
            gld16(&Ks[b ^ 1][off + 4096], Kt + off + 4096);
        }

        // ---- 32x64 score tile: 16 mfma, fold immediately (R7 verified) ----
        #pragma unroll
        for (int ct = 0; ct < 4; ++ct) {
            int rr = ct * 16 + l15;
            bf16x8 b0 = *reinterpret_cast<const bf16x8*>(&Ks[b][swz(rr, 0 * 64 + lg * 16)]);
            bf16x8 b1 = *reinterpret_cast<const bf16x8*>(&Ks[b][swz(rr, 1 * 64 + lg * 16)]);
            #pragma unroll
            for (int rt = 0; rt < 2; ++rt) {
                f32x4 a = {0.f, 0.f, 0.f, 0.f};
                a = __builtin_amdgcn_mfma_f32_16x16x32_bf16(aF[rt][0], b0, a, 0, 0, 0);
                a = __builtin_amdgcn_mfma_f32_16x16x32_bf16(aF[rt][1], b1, a, 0, 0, 0);
                f32x2 v01 = __builtin_shufflevector(a, a, 0, 1);
                f32x2 v23 = __builtin_shufflevector(a, a, 2, 3);
                rsum[rt][0] += v01; rsum[rt][1] += v23;
                rmx[rt][0] = pk_max(rmx[rt][0], v01);
                rmx[rt][1] = pk_max(rmx[rt][1], v23);
                f32x2 e01, e23;
                e01[0] = EXP2(v01[0]); e01[1] = EXP2(v01[1]);
                e23[0] = EXP2(v23[0]); e23[1] = EXP2(v23[1]);
                rs1[rt][0] += e01; rs1[rt][1] += e23;
                rs2[rt][0] = pk_fma(e01, e01, rs2[rt][0]);
                rs2[rt][1] = pk_fma(e23, e23, rs2[rt][1]);
            }
        }

        __syncthreads();   // reads of Ks[b] done; DMA into Ks[b^1] drained
    }

    // ---- reduce across the 16 column-lanes (bits 0..3 of lane id) ----
    #pragma unroll
    for (int m = 1; m < 16; m <<= 1) {
        #pragma unroll
        for (int rt = 0; rt < 2; ++rt)
            #pragma unroll
            for (int c = 0; c < 2; ++c) {
                rsum[rt][c][0] += __shfl_xor(rsum[rt][c][0], m, 64);
                rsum[rt][c][1] += __shfl_xor(rsum[rt][c][1], m, 64);
                rmx[rt][c][0]   = fmaxf(rmx[rt][c][0], __shfl_xor(rmx[rt][c][0], m, 64));
                rmx[rt][c][1]   = fmaxf(rmx[rt][c][1], __shfl_xor(rmx[rt][c][1], m, 64));
                rs1[rt][c][0]  += __shfl_xor(rs1[rt][c][0], m, 64);
                rs1[rt][c][1]  += __shfl_xor(rs1[rt][c][1], m, 64);
                rs2[rt][c][0]  += __shfl_xor(rs2[rt][c][0], m, 64);
                rs2[rt][c][1]  += __shfl_xor(rs2[rt][c][1], m, 64);
            }
    }

    // row-stat layout: rb = (h*KSPLIT + qt)*SQL + global_row_in_head
    const size_t rowbase = ((size_t)(h * KSPLIT + qt)) * SQL + (size_t)qb * QB;
    if (l15 == 0) {
        float bs = 0.f;
        #pragma unroll
        for (int rt = 0; rt < 2; ++rt) {
            const size_t rb = rowbase + (w * 32 + rt * 16 + lg * 4);
            float4 mx = {rmx[rt][0][0] * UNSCALE, rmx[rt][0][1] * UNSCALE,
                         rmx[rt][1][0] * UNSCALE, rmx[rt][1][1] * UNSCALE};
            float4 s1 = {rs1[rt][0][0], rs1[rt][0][1], rs1[rt][1][0], rs1[rt][1][1]};
            float4 s2 = {rs2[rt][0][0], rs2[rt][0][1], rs2[rt][1][0], rs2[rt][1][1]};
            *reinterpret_cast<float4*>(&RMX[rb]) = mx;
            *reinterpret_cast<float4*>(&RS1[rb]) = s1;
            *reinterpret_cast<float4*>(&RS2[rb]) = s2;
            bs += (rsum[rt][0][0] + rsum[rt][0][1]) + (rsum[rt][1][0] + rsum[rt][1][1]);
        }
        red[w * 4 + lg] = bs;
    }
    __syncthreads();
    if (tid == 0) {
        float bs = 0.f;
        #pragma unroll
        for (int i = 0; i < 16; ++i) bs += red[i];
        RSUM[(h * 32 + qb) * KSPLIT + qt] = bs * UNSCALE;
    }
}

// Fallback (ws too small): same geometry, K reg-staged + converted in-loop.
__global__ __launch_bounds__(256, 4) void dtp_stats_reg(const float* __restrict__ Q,
                                                        const float* __restrict__ K,
                                                        float* __restrict__ RSUM,
                                                        float* __restrict__ RMX,
                                                        float* __restrict__ RS1,
                                                        float* __restrict__ RS2) {
    __shared__ __align__(16) unsigned char Ks[2][KIMG];
    __shared__ float red[16];

    const int qb = blockIdx.x, h = blockIdx.y, qt = blockIdx.z;
    const int tid = threadIdx.x, lane = tid & 63, w = tid >> 6;
    const int l15 = lane & 15, lg = lane >> 4;
    const int sc4 = tid & 15, sr = tid >> 4;   // 16 chunks x 16 row-groups

    const float* Kq = K + ((size_t)h * SKL + (size_t)qt * KQ) * DK;

    // prologue: tile0 -> regs -> Ks[0]; prefetch tile1 -> regs
    float4 kreg[4];
    #pragma unroll
    for (int j = 0; j < 4; ++j)
        kreg[j] = *reinterpret_cast<const float4*>(Kq + (size_t)(sr + 16 * j) * DK + sc4 * 4);
    #pragma unroll
    for (int j = 0; j < 4; ++j) {
        int r = sr + 16 * j;
        bf16x4 hv;
        hv[0] = (__bf16)kreg[j].x; hv[1] = (__bf16)kreg[j].y;
        hv[2] = (__bf16)kreg[j].z; hv[3] = (__bf16)kreg[j].w;
        *reinterpret_cast<bf16x4*>(&Ks[0][swz(r, sc4 * 8)]) = hv;
    }
    #pragma unroll
    for (int j = 0; j < 4; ++j)
        kreg[j] = *reinterpret_cast<const float4*>(Kq + (size_t)(KB + sr + 16 * j) * DK + sc4 * 4);

    bf16x8 aF[2][2];
    #pragma unroll
    for (int rt = 0; rt < 2; ++rt) {
        int grow = h * SQL + qb * QB + w * 32 + rt * 16 + l15;
        aF[rt][0] = loadA(Q, grow, 0 * 32 + lg * 8);
        aF[rt][1] = loadA(Q, grow, 1 * 32 + lg * 8);
    }
    __syncthreads();

    f32x2 rsum[2][2], rmx[2][2], rs1[2][2], rs2[2][2];
    #pragma unroll
    for (int rt = 0; rt < 2; ++rt)
        #pragma unroll
        for (int p = 0; p < 2; ++p) {
            rsum[rt][p] = (f32x2){0.f, 0.f};
            rmx[rt][p]  = (f32x2){-3.0e38f, -3.0e38f};
            rs1[rt][p]  = (f32x2){0.f, 0.f};
            rs2[rt][p]  = (f32x2){0.f, 0.f};
        }

    for (int t = 0; t < NKT; ++t) {
        const int b = t & 1;
        if (t + 1 < NKT) {
            #pragma unroll
            for (int j = 0; j < 4; ++j) {
                int r = sr + 16 * j;
                bf16x4 hv;
                hv[0] = (__bf16)kreg[j].x; hv[1] = (__bf16)kreg[j].y;
                hv[2] = (__bf16)kreg[j].z; hv[3] = (__bf16)kreg[j].w;
                *reinterpret_cast<bf16x4*>(&Ks[b ^ 1][swz(r, sc4 * 8)]) = hv;
            }
            if (t + 2 < NKT) {
                const float* Kt = Kq + (size_t)(t + 2) * KB * DK;
                #pragma unroll
                for (int j = 0; j < 4; ++j)
                    kreg[j] = *reinterpret_cast<const float4*>(Kt + (size_t)(sr + 16 * j) * DK + sc4 * 4);
            }
        }
        #pragma unroll
        for (int ct = 0; ct < 4; ++ct) {
            int rr = ct * 16 + l15;
            bf16x8 b0 = *reinterpret_cast<const bf16x8*>(&Ks[b][swz(rr, 0 * 64 + lg * 16)]);
            bf16x8 b1 = *reinterpret_cast<const bf16x8*>(&Ks[b][swz(rr, 1 * 64 + lg * 16)]);
            #pragma unroll
            for (int rt = 0; rt < 2; ++rt) {
                f32x4 a = {0.f, 0.f, 0.f, 0.f};
                a = __builtin_amdgcn_mfma_f32_16x16x32_bf16(aF[rt][0], b0, a, 0, 0, 0);
                a = __builtin_amdgcn_mfma_f32_16x16x32_bf16(aF[rt][1], b1, a, 0, 0, 0);
                f32x2 v01 = __builtin_shufflevector(a, a, 0, 1);
                f32x2 v23 = __builtin_shufflevector(a, a, 2, 3);
                rsum[rt][0] += v01; rsum[rt][1] += v23;
                rmx[rt][0] = pk_max(rmx[rt][0], v01);
                rmx[rt][1] = pk_max(rmx[rt][1], v23);
                f32x2 e01, e23;
                e01[0] = EXP2(v01[0]); e01[1] = EXP2(v01[1]);
                e23[0] = EXP2(v23[0]); e23[1] = EXP2(v23[1]);
                rs1[rt][0] += e01; rs1[rt][1] += e23;
                rs2[rt][0] = pk_fma(e01, e01, rs2[rt][0]);
                rs2[rt][1] = pk_fma(e23, e23, rs2[rt][1]);
            }
        }
        __syncthreads();
    }

    #pragma unroll
    for (int m = 1; m < 16; m <<= 1) {
        #pragma unroll
        for (int rt = 0; rt < 2; ++rt)
            #pragma unroll
            for (int c = 0; c < 2; ++c) {
                rsum[rt][c][0] += __shfl_xor(rsum[rt][c][0], m, 64);
                rsum[rt][c][1] += __shfl_xor(rsum[rt][c][1], m, 64);
                rmx[rt][c][0]   = fmaxf(rmx[rt][c][0], __shfl_xor(rmx[rt][c][0], m, 64));
                rmx[rt][c][1]   = fmaxf(rmx[rt][c][1], __shfl_xor(rmx[rt][c][1], m, 64));
                rs1[rt][c][0]  += __shfl_xor(rs1[rt][c][0], m, 64);
                rs1[rt][c][1]  += __shfl_xor(rs1[rt][c][1], m, 64);
                rs2[rt][c][0]  += __shfl_xor(rs2[rt][c][0], m, 64);
                rs2[rt][c][1]  += __shfl_xor(rs2[rt][c][1], m, 64);
            }
    }

    const size_t rowbase = ((size_t)(h * KSPLIT + qt)) * SQL + (size_t)qb * QB;
    if (l15 == 0) {
        float bs = 0.f;
        #pragma unroll
        for (int rt = 0; rt < 2; ++rt) {
            const size_t rb = rowbase + (w * 32 + rt * 16 + lg * 4);
            float4 mx = {rmx[rt][0][0] * UNSCALE, rmx[rt][0][1] * UNSCALE,
                         rmx[rt][1][0] * UNSCALE, rmx[rt][1][1] * UNSCALE};
            float4 s1 = {rs1[rt][0][0], rs1[rt][0][1], rs1[rt][1][0], rs1[rt][1][1]};
            float4 s2 = {rs2[rt][0][0], rs2[rt][0][1], rs2[rt][1][0], rs2[rt][1][1]};
            *reinterpret_cast<float4*>(&RMX[rb]) = mx;
            *reinterpret_cast<float4*>(&RS1[rb]) = s1;
            *reinterpret_cast<float4*>(&RS2[rb]) = s2;
            bs += (rsum[rt][0][0] + rsum[rt][0][1]) + (rsum[rt][1][0] + rsum[rt][1][1]);
        }
        red[w * 4 + lg] = bs;
    }
    __syncthreads();
    if (tid == 0) {
        float bs = 0.f;
        #pragma unroll
        for (int i = 0; i < 16; ++i) bs += red[i];
        RSUM[(h * 32 + qb) * KSPLIT + qt] = bs * UNSCALE;
    }
}

// Kernel 2: per-head, combine 4 K-quarter partials per row, reduce, MLP.
__global__ __launch_bounds__(256) void dtp_finalize(const float* __restrict__ RSUM,
                                                    const float* __restrict__ RMX,
                                                    const float* __restrict__ RS1,
                                                    const float* __restrict__ RS2,
                                                    const float* __restrict__ W1,
                                                    const float* __restrict__ b1,
                                                    const float* __restrict__ W2,
                                                    const float* __restrict__ b2,
                                                    float* __restrict__ out) {
    const int h   = blockIdx.x;
    const int tid = threadIdx.x;
    const float invSK  = 1.0f / (float)SKL;
    const float invSK1 = 1.0f / (float)(SKL - 1);

    float sm = 0.f, sv = 0.f;
    #pragma unroll
    for (int j = 0; j < 16; ++j) {
        int r = tid + 256 * j;   // 0..4095
        size_t i0 = ((size_t)h * KSPLIT + 0) * SQL + r;
        size_t i1 = i0 + SQL;
        size_t i2 = i0 + 2 * SQL;
        size_t i3 = i0 + 3 * SQL;
        float mx = fmaxf(fmaxf(RMX[i0], RMX[i1]), fmaxf(RMX[i2], RMX[i3]));
        float s1 = (RS1[i0] + RS1[i1]) + (RS1[i2] + RS1[i3]);
        float s2 = (RS2[i0] + RS2[i1]) + (RS2[i2] + RS2[i3]);
        sm += mx;
        sv += (s2 / (s1 * s1) - invSK) * invSK1;
    }
    // 128 block-sums per head (32 qb x 4 quarters)
    float ss = (tid < 128) ? RSUM[h * 128 + tid] : 0.f;

    #pragma unroll
    for (int m = 1; m < 64; m <<= 1) {
        sm += __shfl_xor(sm, m, 64);
        sv += __shfl_xor(sv, m, 64);
        ss += __shfl_xor(ss, m, 64);
    }
    __shared__ float redm[4], redv[4], reds[4];
    const int wv = tid >> 6;
    if ((tid & 63) == 0) { redm[wv] = sm; redv[wv] = sv; reds[wv] = ss; }
    __syncthreads();
    if (tid == 0) {
        float tsm = redm[0] + redm[1] + redm[2] + redm[3];
        float tsv = redv[0] + redv[1] + redv[2] + redv[3];
        float tss = reds[0] + reds[1];   // waves 0,1 loaded RSUM (tid<128)
        float mean_sim = tss / ((float)SQL * (float)SKL);
        float max_sim  = tsm / (float)SQL;
        float entropy  = tsv / (float)SQL;
        mean_sim = fminf(fmaxf(mean_sim, -10.f), 10.f);
        max_sim  = fminf(fmaxf(max_sim,  -10.f), 10.f);
        entropy  = fminf(fmaxf(entropy,    0.f), 1.f);
        float raw = b2[0];
        #pragma unroll
        for (int i = 0; i < 16; ++i) {
            float a = b1[i] + W1[i*3+0] * mean_sim + W1[i*3+1] * max_sim + W1[i*3+2] * entropy;
            raw += W2[i] * tanhf(a);
        }
        float t = 0.1f + 0.9f / (1.0f + __expf(-raw));
        t = fminf(fmaxf(t, 0.1f), 1.0f);
        out[h] = t;
    }
}

extern "C" void kernel_launch(void* const* d_in, const int* in_sizes, int n_in,
                              void* d_out, int out_size, void* d_ws, size_t ws_size,
                              hipStream_t stream) {
    const float* Q  = (const float*)d_in[0];
    const float* K  = (const float*)d_in[1];
    const float* W1 = (const float*)d_in[2];
    const float* b1 = (const float*)d_in[3];
    const float* W2 = (const float*)d_in[4];
    const float* b2 = (const float*)d_in[5];
    float* out      = (float*)d_out;

    float* RSUM = (float*)d_ws;                 // 2048 floats
    float* RMX  = RSUM + RSUMN;                 // 262144
    float* RS1  = RMX + ROWFLOAT;               // 262144
    float* RS2  = RS1 + ROWFLOAT;               // 262144

    const size_t need = STATS_BYTES + KPRE_BYTES;   // ~11.5 MB
    dim3 grid(SQL / QB, NH, KSPLIT);  // (32, 16, 4) = 2048 blocks

    if (ws_size >= need) {
        unsigned char* Kpre = (unsigned char*)d_ws + STATS_BYTES;
        dtp_prepack_k<<<1024, 512, 0, stream>>>(K, Kpre);
        dtp_stats_glds<<<grid, 256, 0, stream>>>(Q, Kpre, RSUM, RMX, RS1, RS2);
    } else {
        dtp_stats_reg<<<grid, 256, 0, stream>>>(Q, K, RSUM, RMX, RS1, RS2);
    }
    dtp_finalize<<<NH, 256, 0, stream>>>(RSUM, RMX, RS1, RS2, W1, b1, W2, b2, out);
}